// Round 1
// baseline (968.440 us; speedup 1.0000x reference)
//
#include <hip/hip_runtime.h>
#include <hip/hip_bf16.h>

#define BATCH 2
#define SEQ 2048
#define HID 1024
#define NHEAD 16
#define HDIM 64
// combined softmax scale: TEMP_K / sqrt(HEAD_DIM) = 1000/8
#define LSCALE 125.0f
#define NEGBIG (-1.0e30f)

// ---------------------------------------------------------------------------
// GEMM1: qkv = x[4096,1024] @ W_qkv[1024,3072] + b_qkv, scattered into
// workspace layout [3][B][NH][SEQ][HDIM]  (q,k,v each [b][h][s][d])
// 128x128 block tile, 256 threads, 8x8 microtile as 2x2 blocks of 4x4.
// ---------------------------------------------------------------------------
__global__ __launch_bounds__(256) void gemm_qkv_kernel(
    const float* __restrict__ X, const float* __restrict__ W,
    const float* __restrict__ bias, float* __restrict__ qkv)
{
    __shared__ __align__(16) float At[16][128];  // At[kk][row]
    __shared__ __align__(16) float Bt[16][128];  // Bt[kk][col]
    const int tid = threadIdx.x;
    const int tx = tid & 15, ty = tid >> 4;
    const int rowBase = blockIdx.y * 128;
    const int colBase = blockIdx.x * 128;

    float acc[2][2][4][4];
#pragma unroll
    for (int a = 0; a < 2; a++)
#pragma unroll
      for (int bq = 0; bq < 2; bq++)
#pragma unroll
        for (int i = 0; i < 4; i++)
#pragma unroll
          for (int j = 0; j < 4; j++) acc[a][bq][i][j] = 0.f;

    const int ar  = tid & 127;        // A staging row
    const int akq = (tid >> 7) * 8;   // A staging k offset (0 or 8)
    const int bkk = tid >> 4;         // B staging k row (0..15)
    const int bc0 = (tid & 15) * 8;   // B staging col offset

    for (int k0 = 0; k0 < HID; k0 += 16) {
        const float4* pa = (const float4*)(X + (size_t)(rowBase + ar) * HID + k0 + akq);
        float4 a0 = pa[0], a1 = pa[1];
        const float4* pb = (const float4*)(W + (size_t)(k0 + bkk) * 3072 + colBase + bc0);
        float4 b0 = pb[0], b1 = pb[1];
        __syncthreads();
        At[akq + 0][ar] = a0.x; At[akq + 1][ar] = a0.y;
        At[akq + 2][ar] = a0.z; At[akq + 3][ar] = a0.w;
        At[akq + 4][ar] = a1.x; At[akq + 5][ar] = a1.y;
        At[akq + 6][ar] = a1.z; At[akq + 7][ar] = a1.w;
        *(float4*)&Bt[bkk][bc0]     = b0;
        *(float4*)&Bt[bkk][bc0 + 4] = b1;
        __syncthreads();
#pragma unroll
        for (int kk = 0; kk < 16; kk++) {
            float4 av0 = *(const float4*)&At[kk][ty * 4];
            float4 av1 = *(const float4*)&At[kk][64 + ty * 4];
            float4 bv0 = *(const float4*)&Bt[kk][tx * 4];
            float4 bv1 = *(const float4*)&Bt[kk][64 + tx * 4];
            float as[2][4] = {{av0.x, av0.y, av0.z, av0.w}, {av1.x, av1.y, av1.z, av1.w}};
            float bs[2][4] = {{bv0.x, bv0.y, bv0.z, bv0.w}, {bv1.x, bv1.y, bv1.z, bv1.w}};
#pragma unroll
            for (int a = 0; a < 2; a++)
#pragma unroll
              for (int bq = 0; bq < 2; bq++)
#pragma unroll
                for (int i = 0; i < 4; i++)
#pragma unroll
                  for (int j = 0; j < 4; j++)
                    acc[a][bq][i][j] += as[a][i] * bs[bq][j];
        }
    }

    // epilogue: scatter into [which][b][h][s][d]
#pragma unroll
    for (int a = 0; a < 2; a++)
#pragma unroll
      for (int i = 0; i < 4; i++) {
        int gr = rowBase + a * 64 + ty * 4 + i;
        int bb = gr >> 11;       // batch
        int ss = gr & 2047;      // seq
#pragma unroll
        for (int bq = 0; bq < 2; bq++) {
            int gc = colBase + bq * 64 + tx * 4;
            int which = gc >> 10;
            int rem = gc & 1023;
            int h = rem >> 6;
            int d = rem & 63;
            float4 bv = *(const float4*)(bias + gc);
            float4 o;
            o.x = acc[a][bq][i][0] + bv.x;
            o.y = acc[a][bq][i][1] + bv.y;
            o.z = acc[a][bq][i][2] + bv.z;
            o.w = acc[a][bq][i][3] + bv.w;
            size_t dst = ((((size_t)which * BATCH + bb) * NHEAD + h) * SEQ + ss) * HDIM + d;
            *(float4*)(qkv + dst) = o;
        }
      }
}

// ---------------------------------------------------------------------------
// Flash-style causal attention, fp32. One block per (qtile, b*h).
// Q-tile 64 rows x 64 dim. Iterate K/V tiles of 64 keys, kt <= qt.
// 256 threads = 16x16; thread (tx,ty) owns scores S[ty*4+i][tx*4+j]
// and output O[ty*4+i][tx*4+j].
// LDS: Qt[d][r], KP[d][c] (K^T during scores, reused as P^T[c][r] during PV),
// Vs[c][d]. Padded to 68 floats/row (16B-aligned rows, conflict-free reads).
// ---------------------------------------------------------------------------
__global__ __launch_bounds__(256) void attn_kernel(
    const float* __restrict__ qkv, float* __restrict__ attnbuf)
{
    __shared__ __align__(16) float Qt[64][68];
    __shared__ __align__(16) float KP[64][68];
    __shared__ __align__(16) float Vs[64][68];

    const int tid = threadIdx.x;
    const int tx = tid & 15, ty = tid >> 4;
    const int qt = gridDim.x - 1 - blockIdx.x;   // heavy tiles first
    const int bh = blockIdx.y;
    const int b = bh >> 4, h = bh & 15;

    const float* Q = qkv + (((size_t)0 * BATCH + b) * NHEAD + h) * SEQ * HDIM;
    const float* K = qkv + (((size_t)1 * BATCH + b) * NHEAD + h) * SEQ * HDIM;
    const float* V = qkv + (((size_t)2 * BATCH + b) * NHEAD + h) * SEQ * HDIM;

    const int c  = tid & 63;   // staging row (seq within tile)
    const int dq = tid >> 6;   // staging d-quarter (0..3), d base dq*16

    // stage Q tile transposed: Qt[d][r]
    {
        const float4* src = (const float4*)(Q + ((size_t)(qt * 64 + c)) * HDIM + dq * 16);
        float4 f0 = src[0], f1 = src[1], f2 = src[2], f3 = src[3];
        float t16[16] = {f0.x, f0.y, f0.z, f0.w, f1.x, f1.y, f1.z, f1.w,
                         f2.x, f2.y, f2.z, f2.w, f3.x, f3.y, f3.z, f3.w};
#pragma unroll
        for (int mI = 0; mI < 16; mI++) Qt[dq * 16 + mI][c] = t16[mI];
    }

    float m[4], l[4], O[4][4];
#pragma unroll
    for (int i = 0; i < 4; i++) {
        m[i] = NEGBIG; l[i] = 0.f;
#pragma unroll
        for (int j = 0; j < 4; j++) O[i][j] = 0.f;
    }

    for (int kt = 0; kt <= qt; kt++) {
        // load K,V tiles to regs
        const float4* ks = (const float4*)(K + ((size_t)(kt * 64 + c)) * HDIM + dq * 16);
        float4 k0 = ks[0], k1 = ks[1], k2 = ks[2], k3 = ks[3];
        const float4* vs = (const float4*)(V + ((size_t)(kt * 64 + c)) * HDIM + dq * 16);
        float4 v0 = vs[0], v1 = vs[1], v2 = vs[2], v3 = vs[3];
        __syncthreads();   // previous iteration done reading KP(P^T)/Vs
        {
            float t16[16] = {k0.x, k0.y, k0.z, k0.w, k1.x, k1.y, k1.z, k1.w,
                             k2.x, k2.y, k2.z, k2.w, k3.x, k3.y, k3.z, k3.w};
#pragma unroll
            for (int mI = 0; mI < 16; mI++) KP[dq * 16 + mI][c] = t16[mI];
        }
        *(float4*)&Vs[c][dq * 16 + 0]  = v0;
        *(float4*)&Vs[c][dq * 16 + 4]  = v1;
        *(float4*)&Vs[c][dq * 16 + 8]  = v2;
        *(float4*)&Vs[c][dq * 16 + 12] = v3;
        __syncthreads();

        // scores: S[i][j] = sum_d Qt[d][ty*4+i] * KP[d][tx*4+j]
        float s[4][4];
#pragma unroll
        for (int i = 0; i < 4; i++)
#pragma unroll
          for (int j = 0; j < 4; j++) s[i][j] = 0.f;
#pragma unroll 4
        for (int d = 0; d < 64; d++) {
            float4 qa = *(const float4*)&Qt[d][ty * 4];
            float4 kb = *(const float4*)&KP[d][tx * 4];
            float qs[4] = {qa.x, qa.y, qa.z, qa.w};
            float kbs[4] = {kb.x, kb.y, kb.z, kb.w};
#pragma unroll
            for (int i = 0; i < 4; i++)
#pragma unroll
              for (int j = 0; j < 4; j++) s[i][j] += qs[i] * kbs[j];
        }

        // logits with causal mask (only diagonal tile needs masking)
        const bool diag = (kt == qt);
#pragma unroll
        for (int i = 0; i < 4; i++)
#pragma unroll
          for (int j = 0; j < 4; j++) {
            float L = s[i][j] * LSCALE;
            if (diag && (tx * 4 + j) > (ty * 4 + i)) L = NEGBIG;
            s[i][j] = L;
          }

        // online softmax update
        float p[4][4];
        float alpha[4], mnew[4];
#pragma unroll
        for (int i = 0; i < 4; i++) {
            float rmax = fmaxf(fmaxf(s[i][0], s[i][1]), fmaxf(s[i][2], s[i][3]));
#pragma unroll
            for (int off = 1; off < 16; off <<= 1)
                rmax = fmaxf(rmax, __shfl_xor(rmax, off, 64));
            mnew[i] = fmaxf(m[i], rmax);
            alpha[i] = __expf(m[i] - mnew[i]);
            float rsum = 0.f;
#pragma unroll
            for (int j = 0; j < 4; j++) {
                p[i][j] = __expf(s[i][j] - mnew[i]);
                rsum += p[i][j];
            }
#pragma unroll
            for (int off = 1; off < 16; off <<= 1)
                rsum += __shfl_xor(rsum, off, 64);
            l[i] = l[i] * alpha[i] + rsum;
            m[i] = mnew[i];
#pragma unroll
            for (int j = 0; j < 4; j++) O[i][j] *= alpha[i];
        }

        __syncthreads();   // done reading KP as K^T
        // write P^T: KP[c][r]
#pragma unroll
        for (int j = 0; j < 4; j++) {
            *(float4*)&KP[tx * 4 + j][ty * 4] =
                make_float4(p[0][j], p[1][j], p[2][j], p[3][j]);
        }
        __syncthreads();

        // PV: O[i][j] += sum_c P^T[c][ty*4+i] * Vs[c][tx*4+j]
#pragma unroll 4
        for (int cc = 0; cc < 64; cc++) {
            float4 pv = *(const float4*)&KP[cc][ty * 4];
            float4 vv = *(const float4*)&Vs[cc][tx * 4];
            float ps[4] = {pv.x, pv.y, pv.z, pv.w};
            float vvs[4] = {vv.x, vv.y, vv.z, vv.w};
#pragma unroll
            for (int i = 0; i < 4; i++)
#pragma unroll
              for (int j = 0; j < 4; j++) O[i][j] += ps[i] * vvs[j];
        }
    }

    // finalize: attnbuf[b][s][h*64+d] = O / l
#pragma unroll
    for (int i = 0; i < 4; i++) {
        float inv = 1.0f / l[i];
        int s_idx = qt * 64 + ty * 4 + i;
        size_t dst = ((size_t)b * SEQ + s_idx) * HID + h * HDIM + tx * 4;
        float4 o;
        o.x = O[i][0] * inv; o.y = O[i][1] * inv;
        o.z = O[i][2] * inv; o.w = O[i][3] * inv;
        *(float4*)(attnbuf + dst) = o;
    }
}

// ---------------------------------------------------------------------------
// GEMM2: out = attn[4096,1024] @ W_out[1024,1024] + b_out  (row-major out)
// ---------------------------------------------------------------------------
__global__ __launch_bounds__(256) void gemm_out_kernel(
    const float* __restrict__ X, const float* __restrict__ W,
    const float* __restrict__ bias, float* __restrict__ out)
{
    __shared__ __align__(16) float At[16][128];
    __shared__ __align__(16) float Bt[16][128];
    const int tid = threadIdx.x;
    const int tx = tid & 15, ty = tid >> 4;
    const int rowBase = blockIdx.y * 128;
    const int colBase = blockIdx.x * 128;

    float acc[2][2][4][4];
#pragma unroll
    for (int a = 0; a < 2; a++)
#pragma unroll
      for (int bq = 0; bq < 2; bq++)
#pragma unroll
        for (int i = 0; i < 4; i++)
#pragma unroll
          for (int j = 0; j < 4; j++) acc[a][bq][i][j] = 0.f;

    const int ar  = tid & 127;
    const int akq = (tid >> 7) * 8;
    const int bkk = tid >> 4;
    const int bc0 = (tid & 15) * 8;

    for (int k0 = 0; k0 < HID; k0 += 16) {
        const float4* pa = (const float4*)(X + (size_t)(rowBase + ar) * HID + k0 + akq);
        float4 a0 = pa[0], a1 = pa[1];
        const float4* pb = (const float4*)(W + (size_t)(k0 + bkk) * HID + colBase + bc0);
        float4 b0 = pb[0], b1 = pb[1];
        __syncthreads();
        At[akq + 0][ar] = a0.x; At[akq + 1][ar] = a0.y;
        At[akq + 2][ar] = a0.z; At[akq + 3][ar] = a0.w;
        At[akq + 4][ar] = a1.x; At[akq + 5][ar] = a1.y;
        At[akq + 6][ar] = a1.z; At[akq + 7][ar] = a1.w;
        *(float4*)&Bt[bkk][bc0]     = b0;
        *(float4*)&Bt[bkk][bc0 + 4] = b1;
        __syncthreads();
#pragma unroll
        for (int kk = 0; kk < 16; kk++) {
            float4 av0 = *(const float4*)&At[kk][ty * 4];
            float4 av1 = *(const float4*)&At[kk][64 + ty * 4];
            float4 bv0 = *(const float4*)&Bt[kk][tx * 4];
            float4 bv1 = *(const float4*)&Bt[kk][64 + tx * 4];
            float as[2][4] = {{av0.x, av0.y, av0.z, av0.w}, {av1.x, av1.y, av1.z, av1.w}};
            float bs[2][4] = {{bv0.x, bv0.y, bv0.z, bv0.w}, {bv1.x, bv1.y, bv1.z, bv1.w}};
#pragma unroll
            for (int a = 0; a < 2; a++)
#pragma unroll
              for (int bq = 0; bq < 2; bq++)
#pragma unroll
                for (int i = 0; i < 4; i++)
#pragma unroll
                  for (int j = 0; j < 4; j++)
                    acc[a][bq][i][j] += as[a][i] * bs[bq][j];
        }
    }

#pragma unroll
    for (int a = 0; a < 2; a++)
#pragma unroll
      for (int i = 0; i < 4; i++) {
        int gr = rowBase + a * 64 + ty * 4 + i;
#pragma unroll
        for (int bq = 0; bq < 2; bq++) {
            int gc = colBase + bq * 64 + tx * 4;
            float4 bv = *(const float4*)(bias + gc);
            float4 o;
            o.x = acc[a][bq][i][0] + bv.x;
            o.y = acc[a][bq][i][1] + bv.y;
            o.z = acc[a][bq][i][2] + bv.z;
            o.w = acc[a][bq][i][3] + bv.w;
            *(float4*)(out + (size_t)gr * HID + gc) = o;
        }
      }
}

extern "C" void kernel_launch(void* const* d_in, const int* in_sizes, int n_in,
                              void* d_out, int out_size, void* d_ws, size_t ws_size,
                              hipStream_t stream) {
    const float* x    = (const float*)d_in[0];
    const float* Wqkv = (const float*)d_in[1];
    const float* bqkv = (const float*)d_in[2];
    const float* Wout = (const float*)d_in[3];
    const float* bout = (const float*)d_in[4];
    float* out = (float*)d_out;

    float* qkv     = (float*)d_ws;                                  // 3*2*16*2048*64 floats
    float* attnbuf = qkv + (size_t)3 * BATCH * NHEAD * SEQ * HDIM;  // 2*2048*1024 floats

    // 1) QKV projection: [4096,1024] @ [1024,3072]
    gemm_qkv_kernel<<<dim3(3072 / 128, 4096 / 128), 256, 0, stream>>>(x, Wqkv, bqkv, qkv);
    // 2) causal flash attention per (qtile, b*h)
    attn_kernel<<<dim3(SEQ / 64, BATCH * NHEAD), 256, 0, stream>>>(qkv, attnbuf);
    // 3) output projection: [4096,1024] @ [1024,1024]
    gemm_out_kernel<<<dim3(HID / 128, 4096 / 128), 256, 0, stream>>>(attnbuf, Wout, bout, out);
}

// Round 2
// 624.981 us; speedup vs baseline: 1.5496x; 1.5496x over previous
//
#include <hip/hip_runtime.h>
#include <hip/hip_bf16.h>

#define BATCH 2
#define SEQ 2048
#define HID 1024
#define NHEAD 16
#define HDIM 64
// combined softmax scale: TEMP_K / sqrt(HEAD_DIM) = 1000/8
#define LSCALE 125.0f
#define NEGBIG (-1.0e30f)

typedef __bf16 bf16;
typedef __bf16 bf16x4 __attribute__((ext_vector_type(4)));
typedef __bf16 bf16x8 __attribute__((ext_vector_type(8)));
typedef float f32x16 __attribute__((ext_vector_type(16)));

// ---------------------------------------------------------------------------
// GEMM1: qkv = x[4096,1024] @ W_qkv[1024,3072] + b_qkv, scattered into
// workspace layout [3][B][NH][SEQ][HDIM]  (q,k,v each [b][h][s][d])
// (unchanged from round 1 — split-bf16 MFMA conversion is next round)
// ---------------------------------------------------------------------------
__global__ __launch_bounds__(256) void gemm_qkv_kernel(
    const float* __restrict__ X, const float* __restrict__ W,
    const float* __restrict__ bias, float* __restrict__ qkv)
{
    __shared__ __align__(16) float At[16][128];  // At[kk][row]
    __shared__ __align__(16) float Bt[16][128];  // Bt[kk][col]
    const int tid = threadIdx.x;
    const int tx = tid & 15, ty = tid >> 4;
    const int rowBase = blockIdx.y * 128;
    const int colBase = blockIdx.x * 128;

    float acc[2][2][4][4];
#pragma unroll
    for (int a = 0; a < 2; a++)
#pragma unroll
      for (int bq = 0; bq < 2; bq++)
#pragma unroll
        for (int i = 0; i < 4; i++)
#pragma unroll
          for (int j = 0; j < 4; j++) acc[a][bq][i][j] = 0.f;

    const int ar  = tid & 127;
    const int akq = (tid >> 7) * 8;
    const int bkk = tid >> 4;
    const int bc0 = (tid & 15) * 8;

    for (int k0 = 0; k0 < HID; k0 += 16) {
        const float4* pa = (const float4*)(X + (size_t)(rowBase + ar) * HID + k0 + akq);
        float4 a0 = pa[0], a1 = pa[1];
        const float4* pb = (const float4*)(W + (size_t)(k0 + bkk) * 3072 + colBase + bc0);
        float4 b0 = pb[0], b1 = pb[1];
        __syncthreads();
        At[akq + 0][ar] = a0.x; At[akq + 1][ar] = a0.y;
        At[akq + 2][ar] = a0.z; At[akq + 3][ar] = a0.w;
        At[akq + 4][ar] = a1.x; At[akq + 5][ar] = a1.y;
        At[akq + 6][ar] = a1.z; At[akq + 7][ar] = a1.w;
        *(float4*)&Bt[bkk][bc0]     = b0;
        *(float4*)&Bt[bkk][bc0 + 4] = b1;
        __syncthreads();
#pragma unroll
        for (int kk = 0; kk < 16; kk++) {
            float4 av0 = *(const float4*)&At[kk][ty * 4];
            float4 av1 = *(const float4*)&At[kk][64 + ty * 4];
            float4 bv0 = *(const float4*)&Bt[kk][tx * 4];
            float4 bv1 = *(const float4*)&Bt[kk][64 + tx * 4];
            float as[2][4] = {{av0.x, av0.y, av0.z, av0.w}, {av1.x, av1.y, av1.z, av1.w}};
            float bs[2][4] = {{bv0.x, bv0.y, bv0.z, bv0.w}, {bv1.x, bv1.y, bv1.z, bv1.w}};
#pragma unroll
            for (int a = 0; a < 2; a++)
#pragma unroll
              for (int bq = 0; bq < 2; bq++)
#pragma unroll
                for (int i = 0; i < 4; i++)
#pragma unroll
                  for (int j = 0; j < 4; j++)
                    acc[a][bq][i][j] += as[a][i] * bs[bq][j];
        }
    }

#pragma unroll
    for (int a = 0; a < 2; a++)
#pragma unroll
      for (int i = 0; i < 4; i++) {
        int gr = rowBase + a * 64 + ty * 4 + i;
        int bb = gr >> 11;
        int ss = gr & 2047;
#pragma unroll
        for (int bq = 0; bq < 2; bq++) {
            int gc = colBase + bq * 64 + tx * 4;
            int which = gc >> 10;
            int rem = gc & 1023;
            int h = rem >> 6;
            int d = rem & 63;
            float4 bv = *(const float4*)(bias + gc);
            float4 o;
            o.x = acc[a][bq][i][0] + bv.x;
            o.y = acc[a][bq][i][1] + bv.y;
            o.z = acc[a][bq][i][2] + bv.z;
            o.w = acc[a][bq][i][3] + bv.w;
            size_t dst = ((((size_t)which * BATCH + bb) * NHEAD + h) * SEQ + ss) * HDIM + d;
            *(float4*)(qkv + dst) = o;
        }
      }
}

// ---------------------------------------------------------------------------
// MFMA flash attention. Q-tile 128 rows (4 waves x 32 q each), K-tile 64.
// Scores: S^T = K·Q^T via v_mfma_f32_32x32x16_bf16, split-bf16 (hi/lo) for
// precision under TEMP=1000. Q hi/lo B-frags live in registers (loop-inv).
// C-layout of S^T: lane owns one q-column (lane&31) x 32 k-rows -> softmax
// is in-lane + one shfl_xor(32); m/l/alpha are per-lane scalars.
// PV: O^T = V^T · P^T with A=Vt[d][c], B=P[q][c] (natural layout, bf16).
// LDS pitch 72 bf16 -> all b128/b64 accesses uniform across bank groups.
// ---------------------------------------------------------------------------
__global__ __launch_bounds__(256) void attn_kernel(
    const float* __restrict__ qkv, float* __restrict__ attnbuf)
{
    __shared__ __align__(16) bf16 Khi[64][72];
    __shared__ __align__(16) bf16 Klo[64][72];
    __shared__ __align__(16) bf16 Vt [64][72];   // Vt[d][c]
    __shared__ __align__(16) bf16 Pb [128][72];  // P[q_local][c]

    const int tid  = threadIdx.x;
    const int wave = tid >> 6;
    const int lane = tid & 63;
    const int lm   = lane & 31;   // q column (for S^T/O^T) / m row (frags)
    const int lq2  = lane >> 5;   // 0..1

    const int qt = 15 - blockIdx.x;   // heavy tiles first
    const int bh = blockIdx.y;
    const int b = bh >> 4, h = bh & 15;

    const float* Q = qkv + (((size_t)0 * BATCH + b) * NHEAD + h) * SEQ * HDIM;
    const float* K = qkv + (((size_t)1 * BATCH + b) * NHEAD + h) * SEQ * HDIM;
    const float* V = qkv + (((size_t)2 * BATCH + b) * NHEAD + h) * SEQ * HDIM;

    // ---- Q B-fragments in registers (hi/lo), loop-invariant ----
    // B[n=q][k=d], frag element j <-> d = c*16 + lq2*8 + j
    const int qg = qt * 128 + wave * 32 + lm;   // my q (global row)
    bf16x8 qh[4], ql[4];
    {
        const float* qp = Q + (size_t)qg * HDIM;
#pragma unroll
        for (int c = 0; c < 4; c++) {
            float4 a = *(const float4*)(qp + c * 16 + lq2 * 8);
            float4 bq = *(const float4*)(qp + c * 16 + lq2 * 8 + 4);
            float xs[8] = {a.x, a.y, a.z, a.w, bq.x, bq.y, bq.z, bq.w};
#pragma unroll
            for (int j = 0; j < 8; j++) {
                bf16 hi = (bf16)xs[j];
                qh[c][j] = hi;
                ql[c][j] = (bf16)(xs[j] - (float)hi);
            }
        }
    }

    // staging assignments
    const int kr  = tid >> 2;          // K row 0..63
    const int kd0 = (tid & 3) * 16;    // K d-offset
    const int vd  = tid & 63;          // V d (Vt row)
    const int vc0 = (tid >> 6) * 16;   // V c-group

    f32x16 O0 = {0.f}, O1 = {0.f};
#pragma unroll
    for (int r = 0; r < 16; r++) { O0[r] = 0.f; O1[r] = 0.f; }
    float m_run = NEGBIG, l_run = 0.f;

    const int ktmax = 2 * qt + 1;
    for (int kt = 0; kt <= ktmax; kt++) {
        // ---- global loads to regs (overlap with prior compute) ----
        const float4* ks = (const float4*)(K + (size_t)(kt * 64 + kr) * HDIM + kd0);
        float4 kf0 = ks[0], kf1 = ks[1], kf2 = ks[2], kf3 = ks[3];
        float vf[16];
#pragma unroll
        for (int i = 0; i < 16; i++)
            vf[i] = V[(size_t)(kt * 64 + vc0 + i) * HDIM + vd];

        __syncthreads();   // prior iteration done reading LDS

        // ---- stage K hi/lo ----
        {
            float kk[16] = {kf0.x, kf0.y, kf0.z, kf0.w, kf1.x, kf1.y, kf1.z, kf1.w,
                            kf2.x, kf2.y, kf2.z, kf2.w, kf3.x, kf3.y, kf3.z, kf3.w};
            bf16x8 h0, h1, l0, l1;
#pragma unroll
            for (int i = 0; i < 8; i++) {
                bf16 hA = (bf16)kk[i];
                bf16 hB = (bf16)kk[i + 8];
                h0[i] = hA; l0[i] = (bf16)(kk[i] - (float)hA);
                h1[i] = hB; l1[i] = (bf16)(kk[i + 8] - (float)hB);
            }
            *(bf16x8*)&Khi[kr][kd0]     = h0;
            *(bf16x8*)&Khi[kr][kd0 + 8] = h1;
            *(bf16x8*)&Klo[kr][kd0]     = l0;
            *(bf16x8*)&Klo[kr][kd0 + 8] = l1;
        }
        // ---- stage V transposed ----
        {
            bf16x8 v0, v1;
#pragma unroll
            for (int i = 0; i < 8; i++) {
                v0[i] = (bf16)vf[i];
                v1[i] = (bf16)vf[i + 8];
            }
            *(bf16x8*)&Vt[vd][vc0]     = v0;
            *(bf16x8*)&Vt[vd][vc0 + 8] = v1;
        }
        __syncthreads();

        // ---- scores: S^T = K · Q^T, split-bf16 (hi*hi + hi*lo + lo*hi) ----
        f32x16 s0 = {0.f}, s1 = {0.f};
#pragma unroll
        for (int r = 0; r < 16; r++) { s0[r] = 0.f; s1[r] = 0.f; }
#pragma unroll
        for (int c = 0; c < 4; c++) {
            bf16x8 kh0 = *(bf16x8*)&Khi[lm][c * 16 + lq2 * 8];
            bf16x8 kl0 = *(bf16x8*)&Klo[lm][c * 16 + lq2 * 8];
            bf16x8 kh1 = *(bf16x8*)&Khi[32 + lm][c * 16 + lq2 * 8];
            bf16x8 kl1 = *(bf16x8*)&Klo[32 + lm][c * 16 + lq2 * 8];
            s0 = __builtin_amdgcn_mfma_f32_32x32x16_bf16(kh0, qh[c], s0, 0, 0, 0);
            s0 = __builtin_amdgcn_mfma_f32_32x32x16_bf16(kh0, ql[c], s0, 0, 0, 0);
            s0 = __builtin_amdgcn_mfma_f32_32x32x16_bf16(kl0, qh[c], s0, 0, 0, 0);
            s1 = __builtin_amdgcn_mfma_f32_32x32x16_bf16(kh1, qh[c], s1, 0, 0, 0);
            s1 = __builtin_amdgcn_mfma_f32_32x32x16_bf16(kh1, ql[c], s1, 0, 0, 0);
            s1 = __builtin_amdgcn_mfma_f32_32x32x16_bf16(kl1, qh[c], s1, 0, 0, 0);
        }

        // ---- logits + causal mask ----
        // C/D layout: row k = (r&3) + 8*(r>>2) + 4*lq2 (+ 32*mt), col q = lm
        float logit[2][16];
        const int kbase = kt * 64 + 4 * lq2;
        const bool needmask = (kt * 64 + 63 > qg);
#pragma unroll
        for (int r = 0; r < 16; r++) {
            int koff = (r & 3) + 8 * (r >> 2);
            float L0 = s0[r] * LSCALE;
            float L1 = s1[r] * LSCALE;
            if (needmask) {
                if (kbase + koff > qg) L0 = NEGBIG;
                if (kbase + 32 + koff > qg) L1 = NEGBIG;
            }
            logit[0][r] = L0;
            logit[1][r] = L1;
        }

        // ---- online softmax (per-lane scalar state) ----
        float vmax = NEGBIG;
#pragma unroll
        for (int r = 0; r < 16; r++)
            vmax = fmaxf(vmax, fmaxf(logit[0][r], logit[1][r]));
        vmax = fmaxf(vmax, __shfl_xor(vmax, 32, 64));
        float mnew = fmaxf(m_run, vmax);
        float alpha = __expf(m_run - mnew);
        float p[2][16];
        float sum = 0.f;
#pragma unroll
        for (int r = 0; r < 16; r++) {
            p[0][r] = __expf(logit[0][r] - mnew);
            p[1][r] = __expf(logit[1][r] - mnew);
            sum += p[0][r] + p[1][r];
        }
        sum += __shfl_xor(sum, 32, 64);
        l_run = l_run * alpha + sum;
        m_run = mnew;
#pragma unroll
        for (int r = 0; r < 16; r++) { O0[r] *= alpha; O1[r] *= alpha; }

        // ---- write P (bf16) to LDS in natural [q][c] layout ----
        // lane owns column q=lm; c = mt*32 + 8*g + 4*lq2 + (0..3) contiguous
#pragma unroll
        for (int mt = 0; mt < 2; mt++)
#pragma unroll
          for (int g = 0; g < 4; g++) {
            bf16x4 pk;
            pk[0] = (bf16)p[mt][4 * g + 0];
            pk[1] = (bf16)p[mt][4 * g + 1];
            pk[2] = (bf16)p[mt][4 * g + 2];
            pk[3] = (bf16)p[mt][4 * g + 3];
            *(bf16x4*)&Pb[wave * 32 + lm][mt * 32 + 8 * g + 4 * lq2] = pk;
          }
        // intra-wave LDS write->read ordering (own rows only, no barrier)
        asm volatile("s_waitcnt lgkmcnt(0)" ::: "memory");

        // ---- PV: O^T += V^T · P^T  (A=Vt[d][c], B=P[q][c]) ----
#pragma unroll
        for (int c = 0; c < 4; c++) {
            bf16x8 pb  = *(bf16x8*)&Pb[wave * 32 + lm][c * 16 + lq2 * 8];
            bf16x8 va0 = *(bf16x8*)&Vt[lm][c * 16 + lq2 * 8];
            bf16x8 va1 = *(bf16x8*)&Vt[32 + lm][c * 16 + lq2 * 8];
            O0 = __builtin_amdgcn_mfma_f32_32x32x16_bf16(va0, pb, O0, 0, 0, 0);
            O1 = __builtin_amdgcn_mfma_f32_32x32x16_bf16(va1, pb, O1, 0, 0, 0);
        }
    }

    // ---- epilogue: attnbuf[b][q][h*64+d] = O^T[d][q] / l ----
    const float inv = 1.0f / l_run;
    float* orow = attnbuf + ((size_t)b * SEQ + qg) * HID + h * HDIM;
#pragma unroll
    for (int g = 0; g < 4; g++) {
        int dbase0 = 8 * g + 4 * lq2;
        float4 o0, o1;
        o0.x = O0[4 * g + 0] * inv; o0.y = O0[4 * g + 1] * inv;
        o0.z = O0[4 * g + 2] * inv; o0.w = O0[4 * g + 3] * inv;
        o1.x = O1[4 * g + 0] * inv; o1.y = O1[4 * g + 1] * inv;
        o1.z = O1[4 * g + 2] * inv; o1.w = O1[4 * g + 3] * inv;
        *(float4*)(orow + dbase0)      = o0;
        *(float4*)(orow + 32 + dbase0) = o1;
    }
}

// ---------------------------------------------------------------------------
// GEMM2: out = attn[4096,1024] @ W_out[1024,1024] + b_out (unchanged)
// ---------------------------------------------------------------------------
__global__ __launch_bounds__(256) void gemm_out_kernel(
    const float* __restrict__ X, const float* __restrict__ W,
    const float* __restrict__ bias, float* __restrict__ out)
{
    __shared__ __align__(16) float At[16][128];
    __shared__ __align__(16) float Bt[16][128];
    const int tid = threadIdx.x;
    const int tx = tid & 15, ty = tid >> 4;
    const int rowBase = blockIdx.y * 128;
    const int colBase = blockIdx.x * 128;

    float acc[2][2][4][4];
#pragma unroll
    for (int a = 0; a < 2; a++)
#pragma unroll
      for (int bq = 0; bq < 2; bq++)
#pragma unroll
        for (int i = 0; i < 4; i++)
#pragma unroll
          for (int j = 0; j < 4; j++) acc[a][bq][i][j] = 0.f;

    const int ar  = tid & 127;
    const int akq = (tid >> 7) * 8;
    const int bkk = tid >> 4;
    const int bc0 = (tid & 15) * 8;

    for (int k0 = 0; k0 < HID; k0 += 16) {
        const float4* pa = (const float4*)(X + (size_t)(rowBase + ar) * HID + k0 + akq);
        float4 a0 = pa[0], a1 = pa[1];
        const float4* pb = (const float4*)(W + (size_t)(k0 + bkk) * HID + colBase + bc0);
        float4 b0 = pb[0], b1 = pb[1];
        __syncthreads();
        At[akq + 0][ar] = a0.x; At[akq + 1][ar] = a0.y;
        At[akq + 2][ar] = a0.z; At[akq + 3][ar] = a0.w;
        At[akq + 4][ar] = a1.x; At[akq + 5][ar] = a1.y;
        At[akq + 6][ar] = a1.z; At[akq + 7][ar] = a1.w;
        *(float4*)&Bt[bkk][bc0]     = b0;
        *(float4*)&Bt[bkk][bc0 + 4] = b1;
        __syncthreads();
#pragma unroll
        for (int kk = 0; kk < 16; kk++) {
            float4 av0 = *(const float4*)&At[kk][ty * 4];
            float4 av1 = *(const float4*)&At[kk][64 + ty * 4];
            float4 bv0 = *(const float4*)&Bt[kk][tx * 4];
            float4 bv1 = *(const float4*)&Bt[kk][64 + tx * 4];
            float as[2][4] = {{av0.x, av0.y, av0.z, av0.w}, {av1.x, av1.y, av1.z, av1.w}};
            float bs[2][4] = {{bv0.x, bv0.y, bv0.z, bv0.w}, {bv1.x, bv1.y, bv1.z, bv1.w}};
#pragma unroll
            for (int a = 0; a < 2; a++)
#pragma unroll
              for (int bq = 0; bq < 2; bq++)
#pragma unroll
                for (int i = 0; i < 4; i++)
#pragma unroll
                  for (int j = 0; j < 4; j++)
                    acc[a][bq][i][j] += as[a][i] * bs[bq][j];
        }
    }

#pragma unroll
    for (int a = 0; a < 2; a++)
#pragma unroll
      for (int i = 0; i < 4; i++) {
        int gr = rowBase + a * 64 + ty * 4 + i;
#pragma unroll
        for (int bq = 0; bq < 2; bq++) {
            int gc = colBase + bq * 64 + tx * 4;
            float4 bv = *(const float4*)(bias + gc);
            float4 o;
            o.x = acc[a][bq][i][0] + bv.x;
            o.y = acc[a][bq][i][1] + bv.y;
            o.z = acc[a][bq][i][2] + bv.z;
            o.w = acc[a][bq][i][3] + bv.w;
            *(float4*)(out + (size_t)gr * HID + gc) = o;
        }
      }
}

extern "C" void kernel_launch(void* const* d_in, const int* in_sizes, int n_in,
                              void* d_out, int out_size, void* d_ws, size_t ws_size,
                              hipStream_t stream) {
    const float* x    = (const float*)d_in[0];
    const float* Wqkv = (const float*)d_in[1];
    const float* bqkv = (const float*)d_in[2];
    const float* Wout = (const float*)d_in[3];
    const float* bout = (const float*)d_in[4];
    float* out = (float*)d_out;

    float* qkv     = (float*)d_ws;
    float* attnbuf = qkv + (size_t)3 * BATCH * NHEAD * SEQ * HDIM;

    gemm_qkv_kernel<<<dim3(3072 / 128, 4096 / 128), 256, 0, stream>>>(x, Wqkv, bqkv, qkv);
    attn_kernel<<<dim3(SEQ / 128, BATCH * NHEAD), 256, 0, stream>>>(qkv, attnbuf);
    gemm_out_kernel<<<dim3(HID / 128, 4096 / 128), 256, 0, stream>>>(attnbuf, Wout, bout, out);
}

// Round 3
// 289.178 us; speedup vs baseline: 3.3489x; 2.1612x over previous
//
#include <hip/hip_runtime.h>
#include <hip/hip_bf16.h>

#define BATCH 2
#define SEQ 2048
#define HID 1024
#define NHEAD 16
#define HDIM 64
// combined softmax scale: TEMP_K / sqrt(HEAD_DIM) = 1000/8
#define LSCALE 125.0f
#define NEGBIG (-1.0e30f)

typedef __bf16 bf16;
typedef __bf16 bf16x4 __attribute__((ext_vector_type(4)));
typedef __bf16 bf16x8 __attribute__((ext_vector_type(8)));
typedef float f32x16 __attribute__((ext_vector_type(16)));

// ---------------------------------------------------------------------------
// Prep: transpose fp32 W[K][N] -> bf16 hi (and optional lo) [N][K].
// 64x64 LDS tile; coalesced loads and stores; LDS pitch 65 (f32) keeps both
// phases <=2-way on banks.
// ---------------------------------------------------------------------------
__global__ __launch_bounds__(256) void transpose_split_kernel(
    const float* __restrict__ W, bf16* __restrict__ Thi, bf16* __restrict__ Tlo,
    int K, int N)
{
    __shared__ float T[64][65];
    const int tid = threadIdx.x;
    const int kBase = blockIdx.y * 64;
    const int nBase = blockIdx.x * 64;
    {
        const int k0 = tid >> 4;          // 0..15
        const int nc = (tid & 15) * 4;
#pragma unroll
        for (int kk = 0; kk < 4; kk++) {
            int k = k0 + kk * 16;
            float4 v = *(const float4*)(W + (size_t)(kBase + k) * N + nBase + nc);
            T[k][nc] = v.x; T[k][nc + 1] = v.y; T[k][nc + 2] = v.z; T[k][nc + 3] = v.w;
        }
    }
    __syncthreads();
    {
        const int n = tid >> 2;
        const int kc = (tid & 3) * 16;
        bf16x8 h0, h1, l0, l1;
#pragma unroll
        for (int j = 0; j < 8; j++) {
            float a = T[kc + j][n];
            float c = T[kc + 8 + j][n];
            bf16 ha = (bf16)a, hc = (bf16)c;
            h0[j] = ha; h1[j] = hc;
            l0[j] = (bf16)(a - (float)ha);
            l1[j] = (bf16)(c - (float)hc);
        }
        size_t dst = (size_t)(nBase + n) * K + kBase + kc;
        *(bf16x8*)(Thi + dst)     = h0;
        *(bf16x8*)(Thi + dst + 8) = h1;
        if (Tlo) {
            *(bf16x8*)(Tlo + dst)     = l0;
            *(bf16x8*)(Tlo + dst + 8) = l1;
        }
    }
}

// ---------------------------------------------------------------------------
// GEMM1 (MFMA): qkv = x[4096,1024] @ W_qkv[1024,3072] + b_qkv.
// Transposed orientation: D^T = mfma(A=W^T rows [n][k], B=X rows [m][k]) so
// the epilogue lane owns one sequence row with d-contiguous columns.
// Q/K blocks: 3-pass split-bf16 (precision under TEMP=1000); V blocks
// (nBase>=2048): plain bf16. Outputs bf16 q hi/lo, k hi/lo, v in [b][h][s][d].
// LDS pitch 40 bf16 (20 dwords): frag reads perfectly tile 32 banks.
// ---------------------------------------------------------------------------
__global__ __launch_bounds__(256) void gemm_qkv_mfma(
    const float* __restrict__ X, const bf16* __restrict__ Wthi,
    const bf16* __restrict__ Wtlo, const float* __restrict__ bias,
    bf16* __restrict__ qhi, bf16* __restrict__ qlo,
    bf16* __restrict__ khi, bf16* __restrict__ klo, bf16* __restrict__ vv)
{
    __shared__ __align__(16) bf16 Xh[128][40];
    __shared__ __align__(16) bf16 Xl[128][40];
    __shared__ __align__(16) bf16 Wh[128][40];
    __shared__ __align__(16) bf16 Wl[128][40];

    const int tid = threadIdx.x;
    const int wave = tid >> 6, lane = tid & 63;
    const int lm = lane & 31, lq2 = lane >> 5;
    const int wave_s = wave & 1, wave_n = wave >> 1;
    const int nBase = blockIdx.x * 128;
    const int sBase = blockIdx.y * 128;
    const bool isV = (nBase >= 2 * HID);

    const int sr = tid >> 1, skc = (tid & 1) * 16;  // staging row / k-chunk

    f32x16 acc[2][2];
#pragma unroll
    for (int st = 0; st < 2; st++)
#pragma unroll
      for (int nt = 0; nt < 2; nt++)
#pragma unroll
        for (int r = 0; r < 16; r++) acc[st][nt][r] = 0.f;

    for (int k0 = 0; k0 < HID; k0 += 32) {
        // ---- global loads ----
        const float4* px = (const float4*)(X + (size_t)(sBase + sr) * HID + k0 + skc);
        float4 x0 = px[0], x1 = px[1], x2 = px[2], x3 = px[3];
        size_t wsrc = (size_t)(nBase + sr) * HID + k0 + skc;
        bf16x8 wh0 = *(const bf16x8*)(Wthi + wsrc);
        bf16x8 wh1 = *(const bf16x8*)(Wthi + wsrc + 8);
        bf16x8 wl0 = {}, wl1 = {};
        if (!isV) {
            wl0 = *(const bf16x8*)(Wtlo + wsrc);
            wl1 = *(const bf16x8*)(Wtlo + wsrc + 8);
        }
        __syncthreads();
        // ---- stage X hi/lo ----
        {
            float xs[16] = {x0.x, x0.y, x0.z, x0.w, x1.x, x1.y, x1.z, x1.w,
                            x2.x, x2.y, x2.z, x2.w, x3.x, x3.y, x3.z, x3.w};
            bf16x8 hh0, hh1;
#pragma unroll
            for (int j = 0; j < 8; j++) { hh0[j] = (bf16)xs[j]; hh1[j] = (bf16)xs[j + 8]; }
            *(bf16x8*)&Xh[sr][skc]     = hh0;
            *(bf16x8*)&Xh[sr][skc + 8] = hh1;
            if (!isV) {
                bf16x8 ll0, ll1;
#pragma unroll
                for (int j = 0; j < 8; j++) {
                    ll0[j] = (bf16)(xs[j] - (float)hh0[j]);
                    ll1[j] = (bf16)(xs[j + 8] - (float)hh1[j]);
                }
                *(bf16x8*)&Xl[sr][skc]     = ll0;
                *(bf16x8*)&Xl[sr][skc + 8] = ll1;
            }
        }
        *(bf16x8*)&Wh[sr][skc]     = wh0;
        *(bf16x8*)&Wh[sr][skc + 8] = wh1;
        if (!isV) {
            *(bf16x8*)&Wl[sr][skc]     = wl0;
            *(bf16x8*)&Wl[sr][skc + 8] = wl1;
        }
        __syncthreads();

        // ---- MFMA ----
#pragma unroll
        for (int kh = 0; kh < 2; kh++) {
            const int ko = kh * 16 + lq2 * 8;
            bf16x8 aWh[2], aWl[2], bXh[2], bXl[2];
#pragma unroll
            for (int nt = 0; nt < 2; nt++) {
                aWh[nt] = *(bf16x8*)&Wh[wave_n * 64 + nt * 32 + lm][ko];
                if (!isV) aWl[nt] = *(bf16x8*)&Wl[wave_n * 64 + nt * 32 + lm][ko];
            }
#pragma unroll
            for (int st = 0; st < 2; st++) {
                bXh[st] = *(bf16x8*)&Xh[wave_s * 64 + st * 32 + lm][ko];
                if (!isV) bXl[st] = *(bf16x8*)&Xl[wave_s * 64 + st * 32 + lm][ko];
            }
#pragma unroll
            for (int nt = 0; nt < 2; nt++)
#pragma unroll
              for (int st = 0; st < 2; st++) {
                acc[st][nt] = __builtin_amdgcn_mfma_f32_32x32x16_bf16(aWh[nt], bXh[st], acc[st][nt], 0, 0, 0);
                if (!isV) {
                    acc[st][nt] = __builtin_amdgcn_mfma_f32_32x32x16_bf16(aWh[nt], bXl[st], acc[st][nt], 0, 0, 0);
                    acc[st][nt] = __builtin_amdgcn_mfma_f32_32x32x16_bf16(aWl[nt], bXh[st], acc[st][nt], 0, 0, 0);
                }
              }
        }
    }

    // ---- epilogue: lane owns seq-row s (per st); cols n quad-contiguous ----
#pragma unroll
    for (int st = 0; st < 2; st++) {
        int s = sBase + wave_s * 64 + st * 32 + lm;
        int bb = s >> 11, ss = s & 2047;
#pragma unroll
        for (int nt = 0; nt < 2; nt++) {
#pragma unroll
            for (int q4 = 0; q4 < 4; q4++) {
                int n = nBase + wave_n * 64 + nt * 32 + 8 * q4 + 4 * lq2;
                float4 bv = *(const float4*)(bias + n);
                float vals[4];
                vals[0] = acc[st][nt][q4 * 4 + 0] + bv.x;
                vals[1] = acc[st][nt][q4 * 4 + 1] + bv.y;
                vals[2] = acc[st][nt][q4 * 4 + 2] + bv.z;
                vals[3] = acc[st][nt][q4 * 4 + 3] + bv.w;
                int which = n >> 10, h = (n >> 6) & 15, d = n & 63;
                size_t dst = (((size_t)bb * NHEAD + h) * SEQ + ss) * HDIM + d;
                if (which < 2) {
                    bf16x4 hi4, lo4;
#pragma unroll
                    for (int i = 0; i < 4; i++) {
                        hi4[i] = (bf16)vals[i];
                        lo4[i] = (bf16)(vals[i] - (float)hi4[i]);
                    }
                    bf16* ph = (which == 0) ? qhi : khi;
                    bf16* pl = (which == 0) ? qlo : klo;
                    *(bf16x4*)(ph + dst) = hi4;
                    *(bf16x4*)(pl + dst) = lo4;
                } else {
                    bf16x4 v4;
#pragma unroll
                    for (int i = 0; i < 4; i++) v4[i] = (bf16)vals[i];
                    *(bf16x4*)(vv + dst) = v4;
                }
            }
        }
    }
}

// ---------------------------------------------------------------------------
// MFMA flash attention (bf16-split inputs). Q-tile 128 (4 waves x 32 q),
// K-tile 64. S^T = K·Q^T (3-pass split), O^T = V^T·P^T (plain bf16).
// Inputs pre-split by gemm_qkv_mfma; output attnbuf bf16 [b][s][hid].
// ---------------------------------------------------------------------------
__global__ __launch_bounds__(256) void attn_kernel(
    const bf16* __restrict__ Qhi, const bf16* __restrict__ Qlo,
    const bf16* __restrict__ Khg, const bf16* __restrict__ Klg,
    const bf16* __restrict__ Vg, bf16* __restrict__ attnbuf)
{
    __shared__ __align__(16) bf16 Khs[64][72];
    __shared__ __align__(16) bf16 Kls[64][72];
    __shared__ __align__(16) bf16 Vt [64][72];   // Vt[d][c]
    __shared__ __align__(16) bf16 Pb [128][72];  // P[q_local][c]

    const int tid  = threadIdx.x;
    const int wave = tid >> 6;
    const int lane = tid & 63;
    const int lm   = lane & 31;
    const int lq2  = lane >> 5;

    const int qt = 15 - blockIdx.x;   // heavy tiles first
    const int bh = blockIdx.y;
    const int b = bh >> 4, h = bh & 15;
    const size_t headoff = ((size_t)b * NHEAD + h) * SEQ * HDIM;

    // ---- Q B-fragments in registers (hi/lo), loop-invariant ----
    const int qg = qt * 128 + wave * 32 + lm;
    bf16x8 qh[4], ql[4];
    {
        const bf16* qph = Qhi + headoff + (size_t)qg * HDIM;
        const bf16* qpl = Qlo + headoff + (size_t)qg * HDIM;
#pragma unroll
        for (int c = 0; c < 4; c++) {
            qh[c] = *(const bf16x8*)(qph + c * 16 + lq2 * 8);
            ql[c] = *(const bf16x8*)(qpl + c * 16 + lq2 * 8);
        }
    }

    const int kr  = tid >> 2;          // K row 0..63
    const int kd0 = (tid & 3) * 16;    // K d-offset
    const int vd  = tid & 63;          // V d (Vt row)
    const int vc0 = (tid >> 6) * 16;   // V c-group

    f32x16 O0, O1;
#pragma unroll
    for (int r = 0; r < 16; r++) { O0[r] = 0.f; O1[r] = 0.f; }
    float m_run = NEGBIG, l_run = 0.f;

    const int ktmax = 2 * qt + 1;
    for (int kt = 0; kt <= ktmax; kt++) {
        // ---- global loads to regs ----
        size_t kbase_g = headoff + (size_t)(kt * 64 + kr) * HDIM + kd0;
        bf16x8 kh0 = *(const bf16x8*)(Khg + kbase_g);
        bf16x8 kh1 = *(const bf16x8*)(Khg + kbase_g + 8);
        bf16x8 kl0 = *(const bf16x8*)(Klg + kbase_g);
        bf16x8 kl1 = *(const bf16x8*)(Klg + kbase_g + 8);
        bf16 vtmp[16];
#pragma unroll
        for (int i = 0; i < 16; i++)
            vtmp[i] = Vg[headoff + (size_t)(kt * 64 + vc0 + i) * HDIM + vd];

        __syncthreads();   // prior iteration done reading LDS

        *(bf16x8*)&Khs[kr][kd0]     = kh0;
        *(bf16x8*)&Khs[kr][kd0 + 8] = kh1;
        *(bf16x8*)&Kls[kr][kd0]     = kl0;
        *(bf16x8*)&Kls[kr][kd0 + 8] = kl1;
        {
            bf16x8 v0, v1;
#pragma unroll
            for (int i = 0; i < 8; i++) { v0[i] = vtmp[i]; v1[i] = vtmp[i + 8]; }
            *(bf16x8*)&Vt[vd][vc0]     = v0;
            *(bf16x8*)&Vt[vd][vc0 + 8] = v1;
        }
        __syncthreads();

        // ---- scores: S^T = K · Q^T (hi*hi + hi*lo + lo*hi) ----
        f32x16 s0, s1;
#pragma unroll
        for (int r = 0; r < 16; r++) { s0[r] = 0.f; s1[r] = 0.f; }
#pragma unroll
        for (int c = 0; c < 4; c++) {
            bf16x8 ah0 = *(bf16x8*)&Khs[lm][c * 16 + lq2 * 8];
            bf16x8 al0 = *(bf16x8*)&Kls[lm][c * 16 + lq2 * 8];
            bf16x8 ah1 = *(bf16x8*)&Khs[32 + lm][c * 16 + lq2 * 8];
            bf16x8 al1 = *(bf16x8*)&Kls[32 + lm][c * 16 + lq2 * 8];
            s0 = __builtin_amdgcn_mfma_f32_32x32x16_bf16(ah0, qh[c], s0, 0, 0, 0);
            s0 = __builtin_amdgcn_mfma_f32_32x32x16_bf16(ah0, ql[c], s0, 0, 0, 0);
            s0 = __builtin_amdgcn_mfma_f32_32x32x16_bf16(al0, qh[c], s0, 0, 0, 0);
            s1 = __builtin_amdgcn_mfma_f32_32x32x16_bf16(ah1, qh[c], s1, 0, 0, 0);
            s1 = __builtin_amdgcn_mfma_f32_32x32x16_bf16(ah1, ql[c], s1, 0, 0, 0);
            s1 = __builtin_amdgcn_mfma_f32_32x32x16_bf16(al1, qh[c], s1, 0, 0, 0);
        }

        // ---- logits + causal mask ----
        float logit[2][16];
        const int kbase = kt * 64 + 4 * lq2;
        const bool needmask = (kt * 64 + 63 > qg);
#pragma unroll
        for (int r = 0; r < 16; r++) {
            int koff = (r & 3) + 8 * (r >> 2);
            float L0 = s0[r] * LSCALE;
            float L1 = s1[r] * LSCALE;
            if (needmask) {
                if (kbase + koff > qg) L0 = NEGBIG;
                if (kbase + 32 + koff > qg) L1 = NEGBIG;
            }
            logit[0][r] = L0;
            logit[1][r] = L1;
        }

        // ---- online softmax (per-lane scalar state) ----
        float vmax = NEGBIG;
#pragma unroll
        for (int r = 0; r < 16; r++)
            vmax = fmaxf(vmax, fmaxf(logit[0][r], logit[1][r]));
        vmax = fmaxf(vmax, __shfl_xor(vmax, 32, 64));
        float mnew = fmaxf(m_run, vmax);
        float alpha = __expf(m_run - mnew);
        float p[2][16];
        float sum = 0.f;
#pragma unroll
        for (int r = 0; r < 16; r++) {
            p[0][r] = __expf(logit[0][r] - mnew);
            p[1][r] = __expf(logit[1][r] - mnew);
            sum += p[0][r] + p[1][r];
        }
        sum += __shfl_xor(sum, 32, 64);
        l_run = l_run * alpha + sum;
        m_run = mnew;
#pragma unroll
        for (int r = 0; r < 16; r++) { O0[r] *= alpha; O1[r] *= alpha; }

        // ---- write P (bf16) to LDS in natural [q][c] layout ----
#pragma unroll
        for (int mt = 0; mt < 2; mt++)
#pragma unroll
          for (int g = 0; g < 4; g++) {
            bf16x4 pk;
            pk[0] = (bf16)p[mt][4 * g + 0];
            pk[1] = (bf16)p[mt][4 * g + 1];
            pk[2] = (bf16)p[mt][4 * g + 2];
            pk[3] = (bf16)p[mt][4 * g + 3];
            *(bf16x4*)&Pb[wave * 32 + lm][mt * 32 + 8 * g + 4 * lq2] = pk;
          }
        asm volatile("s_waitcnt lgkmcnt(0)" ::: "memory");

        // ---- PV: O^T += V^T · P^T ----
#pragma unroll
        for (int c = 0; c < 4; c++) {
            bf16x8 pb  = *(bf16x8*)&Pb[wave * 32 + lm][c * 16 + lq2 * 8];
            bf16x8 va0 = *(bf16x8*)&Vt[lm][c * 16 + lq2 * 8];
            bf16x8 va1 = *(bf16x8*)&Vt[32 + lm][c * 16 + lq2 * 8];
            O0 = __builtin_amdgcn_mfma_f32_32x32x16_bf16(va0, pb, O0, 0, 0, 0);
            O1 = __builtin_amdgcn_mfma_f32_32x32x16_bf16(va1, pb, O1, 0, 0, 0);
        }
    }

    // ---- epilogue: attnbuf[b][q][h*64+d] = O^T[d][q] / l  (bf16) ----
    const float inv = 1.0f / l_run;
    bf16* orow = attnbuf + ((size_t)b * SEQ + qg) * HID + h * HDIM;
#pragma unroll
    for (int g = 0; g < 4; g++) {
        int d0 = 8 * g + 4 * lq2;
        bf16x4 o0, o1;
#pragma unroll
        for (int i = 0; i < 4; i++) {
            o0[i] = (bf16)(O0[4 * g + i] * inv);
            o1[i] = (bf16)(O1[4 * g + i] * inv);
        }
        *(bf16x4*)(orow + d0)      = o0;
        *(bf16x4*)(orow + 32 + d0) = o1;
    }
}

// ---------------------------------------------------------------------------
// GEMM2 (MFMA, plain bf16): out = attn[4096,1024] @ W_out + b_out.
// Transposed orientation: lane owns one output row m, cols quad-contiguous
// -> float4 stores.
// ---------------------------------------------------------------------------
__global__ __launch_bounds__(256) void gemm_out_mfma(
    const bf16* __restrict__ Attn, const bf16* __restrict__ Wt,
    const float* __restrict__ bias, float* __restrict__ out)
{
    __shared__ __align__(16) bf16 Ah[128][40];  // Wt rows [n][k] (A-operand)
    __shared__ __align__(16) bf16 Bh[128][40];  // attn rows [m][k] (B-operand)

    const int tid = threadIdx.x;
    const int wave = tid >> 6, lane = tid & 63;
    const int lm = lane & 31, lq2 = lane >> 5;
    const int wave_m = wave & 1, wave_n = wave >> 1;
    const int nBase = blockIdx.x * 128;
    const int mBase = blockIdx.y * 128;

    const int sr = tid >> 1, skc = (tid & 1) * 16;

    f32x16 acc[2][2];
#pragma unroll
    for (int mt = 0; mt < 2; mt++)
#pragma unroll
      for (int nt = 0; nt < 2; nt++)
#pragma unroll
        for (int r = 0; r < 16; r++) acc[mt][nt][r] = 0.f;

    for (int k0 = 0; k0 < HID; k0 += 32) {
        size_t asrc = (size_t)(nBase + sr) * HID + k0 + skc;
        size_t bsrc = (size_t)(mBase + sr) * HID + k0 + skc;
        bf16x8 a0 = *(const bf16x8*)(Wt + asrc);
        bf16x8 a1 = *(const bf16x8*)(Wt + asrc + 8);
        bf16x8 b0 = *(const bf16x8*)(Attn + bsrc);
        bf16x8 b1 = *(const bf16x8*)(Attn + bsrc + 8);
        __syncthreads();
        *(bf16x8*)&Ah[sr][skc]     = a0;
        *(bf16x8*)&Ah[sr][skc + 8] = a1;
        *(bf16x8*)&Bh[sr][skc]     = b0;
        *(bf16x8*)&Bh[sr][skc + 8] = b1;
        __syncthreads();
#pragma unroll
        for (int kh = 0; kh < 2; kh++) {
            const int ko = kh * 16 + lq2 * 8;
            bf16x8 aW[2], bA[2];
#pragma unroll
            for (int nt = 0; nt < 2; nt++)
                aW[nt] = *(bf16x8*)&Ah[wave_n * 64 + nt * 32 + lm][ko];
#pragma unroll
            for (int mt = 0; mt < 2; mt++)
                bA[mt] = *(bf16x8*)&Bh[wave_m * 64 + mt * 32 + lm][ko];
#pragma unroll
            for (int nt = 0; nt < 2; nt++)
#pragma unroll
              for (int mt = 0; mt < 2; mt++)
                acc[mt][nt] = __builtin_amdgcn_mfma_f32_32x32x16_bf16(aW[nt], bA[mt], acc[mt][nt], 0, 0, 0);
        }
    }

#pragma unroll
    for (int mt = 0; mt < 2; mt++) {
        int m = mBase + wave_m * 64 + mt * 32 + lm;
#pragma unroll
        for (int nt = 0; nt < 2; nt++) {
#pragma unroll
            for (int q4 = 0; q4 < 4; q4++) {
                int n = nBase + wave_n * 64 + nt * 32 + 8 * q4 + 4 * lq2;
                float4 bv = *(const float4*)(bias + n);
                float4 o;
                o.x = acc[mt][nt][q4 * 4 + 0] + bv.x;
                o.y = acc[mt][nt][q4 * 4 + 1] + bv.y;
                o.z = acc[mt][nt][q4 * 4 + 2] + bv.z;
                o.w = acc[mt][nt][q4 * 4 + 3] + bv.w;
                *(float4*)(out + (size_t)m * HID + n) = o;
            }
        }
    }
}

extern "C" void kernel_launch(void* const* d_in, const int* in_sizes, int n_in,
                              void* d_out, int out_size, void* d_ws, size_t ws_size,
                              hipStream_t stream) {
    const float* x    = (const float*)d_in[0];
    const float* Wqkv = (const float*)d_in[1];
    const float* bqkv = (const float*)d_in[2];
    const float* Wout = (const float*)d_in[3];
    const float* bout = (const float*)d_in[4];
    float* out = (float*)d_out;

    // workspace layout (bf16 elements), total ~65.0 MB
    const size_t NW  = (size_t)HID * 3 * HID;            // 3.15M (W_qkv^T)
    const size_t NWo = (size_t)HID * HID;                // 1.05M
    const size_t NT  = (size_t)BATCH * NHEAD * SEQ * HDIM; // 4.19M per tensor
    bf16* Wthi = (bf16*)d_ws;
    bf16* Wtlo = Wthi + NW;
    bf16* Wot  = Wtlo + NW;
    bf16* qhi  = Wot + NWo;
    bf16* qlo  = qhi + NT;
    bf16* khi  = qlo + NT;
    bf16* klo  = khi + NT;
    bf16* vv   = klo + NT;
    bf16* attnbuf = vv + NT;

    // 0) weight preps
    transpose_split_kernel<<<dim3(3 * HID / 64, HID / 64), 256, 0, stream>>>(
        Wqkv, Wthi, Wtlo, HID, 3 * HID);
    transpose_split_kernel<<<dim3(HID / 64, HID / 64), 256, 0, stream>>>(
        Wout, Wot, nullptr, HID, HID);
    // 1) QKV projection (split-bf16 MFMA), bf16 split outputs
    gemm_qkv_mfma<<<dim3(3 * HID / 128, BATCH * SEQ / 128), 256, 0, stream>>>(
        x, Wthi, Wtlo, bqkv, qhi, qlo, khi, klo, vv);
    // 2) causal flash attention (MFMA)
    attn_kernel<<<dim3(SEQ / 128, BATCH * NHEAD), 256, 0, stream>>>(
        qhi, qlo, khi, klo, vv, attnbuf);
    // 3) output projection (plain bf16 MFMA)
    gemm_out_mfma<<<dim3(HID / 128, BATCH * SEQ / 128), 256, 0, stream>>>(
        attnbuf, Wot, bout, out);
}